// Round 4
// baseline (1597.696 us; speedup 1.0000x reference)
//
#include <hip/hip_runtime.h>

// RGCN block-diagonal layer, f32.
// out = relu( (scatter_sum(msg) * norm) + bias + h @ loop_weight )
// msg[e, b*16+o] = sum_i h[src[e], b*16+i] * W[type[e], b*256 + i*16 + o]
//
// v4 pipeline (gather formulation -- no global atomics, no LDS accum):
//   A: init_kernel : out[n][:] = bias + h[n] @ loop_weight   (LDS-staged LW)
//   T: transpose weights -> wT[t][bb][o][i]  (ws, 128 KB, L2-hot)
//   Z: zero cnt
//   H: histogram over dst (N bins)
//   S: single-block scan -> row_ptr (CSR), cursor
//   C: scatter srec[p] = (src<<4)|type, sorted by dst
//   G: gather : one WAVE per dst; walk its edges; 8 bcast float4 h-loads +
//      8 vector float4 wT loads + 32 FMA; acc in VGPRs;
//      out[d] = relu(out[d] + acc*norm[d])   (non-atomic, fused relu)

__global__ __launch_bounds__(256) void rgcn_init_kernel(
    const float* __restrict__ h, const float* __restrict__ loop_w,
    const float* __restrict__ bias, float* __restrict__ out, int N) {
  __shared__ float lw[128 * 128];  // 64 KB
  for (int idx = threadIdx.x; idx < 128 * 128 / 4; idx += 256) {
    ((float4*)lw)[idx] = ((const float4*)loop_w)[idx];
  }
  __syncthreads();

  const int lane = threadIdx.x & 63;
  const int wid = threadIdx.x >> 6;
  const int group0 = blockIdx.x * 4 + wid;
  const int ngroups = gridDim.x * 4;
  const int totgroups = (N + 3) >> 2;
  const float b0 = bias[lane];
  const float b1 = bias[64 + lane];

  for (int g = group0; g < totgroups; g += ngroups) {
    const int n0 = g * 4;
    const int nn = (N - n0 < 4) ? (N - n0) : 4;
    if (nn == 4) {
      const float* __restrict__ r0 = h + (size_t)n0 * 128;
      const float* __restrict__ r1 = r0 + 128;
      const float* __restrict__ r2 = r1 + 128;
      const float* __restrict__ r3 = r2 + 128;
      float a00 = b0, a01 = b1, a10 = b0, a11 = b1;
      float a20 = b0, a21 = b1, a30 = b0, a31 = b1;
#pragma unroll 4
      for (int k = 0; k < 128; ++k) {
        const float w0 = lw[k * 128 + lane];
        const float w1 = lw[k * 128 + 64 + lane];
        a00 = fmaf(r0[k], w0, a00); a01 = fmaf(r0[k], w1, a01);
        a10 = fmaf(r1[k], w0, a10); a11 = fmaf(r1[k], w1, a11);
        a20 = fmaf(r2[k], w0, a20); a21 = fmaf(r2[k], w1, a21);
        a30 = fmaf(r3[k], w0, a30); a31 = fmaf(r3[k], w1, a31);
      }
      float* __restrict__ o0 = out + (size_t)n0 * 128;
      o0[lane] = a00;        o0[64 + lane] = a01;
      o0[128 + lane] = a10;  o0[192 + lane] = a11;
      o0[256 + lane] = a20;  o0[320 + lane] = a21;
      o0[384 + lane] = a30;  o0[448 + lane] = a31;
    } else {
      for (int r = 0; r < nn; ++r) {
        const int n = n0 + r;
        const float* __restrict__ hr = h + (size_t)n * 128;
        float a0 = b0, a1 = b1;
#pragma unroll 4
        for (int k = 0; k < 128; ++k) {
          const float a = hr[k];
          a0 = fmaf(a, lw[k * 128 + lane], a0);
          a1 = fmaf(a, lw[k * 128 + 64 + lane], a1);
        }
        out[(size_t)n * 128 + lane] = a0;
        out[(size_t)n * 128 + 64 + lane] = a1;
      }
    }
  }
}

// wT[t][bb][o][i] = weight[t][bb][i][o]   (32768 floats)
__global__ __launch_bounds__(256) void rgcn_transpose_w_kernel(
    const float* __restrict__ weight, float* __restrict__ wT, int total) {
  for (int idx = blockIdx.x * 256 + threadIdx.x; idx < total;
       idx += gridDim.x * 256) {
    const int t = idx >> 11;
    const int r = idx & 2047;
    const int bb = r >> 8;
    const int i = (r >> 4) & 15;
    const int o = r & 15;
    wT[t * 2048 + bb * 256 + o * 16 + i] = weight[idx];
  }
}

__global__ __launch_bounds__(256) void rgcn_zero_kernel(int* __restrict__ p,
                                                        int n) {
  for (int i = blockIdx.x * 256 + threadIdx.x; i < n; i += gridDim.x * 256)
    p[i] = 0;
}

__global__ __launch_bounds__(256) void rgcn_hist_kernel(
    const int* __restrict__ edst, int* __restrict__ cnt, int E) {
  for (int e = blockIdx.x * 256 + threadIdx.x; e < E; e += gridDim.x * 256)
    atomicAdd(&cnt[edst[e]], 1);
}

__global__ __launch_bounds__(1024) void rgcn_scan_kernel(
    const int* __restrict__ cnt, int* __restrict__ row_ptr,
    int* __restrict__ cursor, int bins) {
  __shared__ int part[1024];
  const int t = threadIdx.x;
  const int chunk = (bins + 1023) >> 10;
  const int lo = t * chunk;
  const int hi = min(bins, lo + chunk);
  int s = 0;
  for (int i = lo; i < hi; ++i) s += cnt[i];
  part[t] = s;
  __syncthreads();
#pragma unroll
  for (int off = 1; off < 1024; off <<= 1) {
    const int add = (t >= off) ? part[t - off] : 0;
    __syncthreads();
    part[t] += add;
    __syncthreads();
  }
  int run = (t == 0) ? 0 : part[t - 1];
  for (int i = lo; i < hi; ++i) {
    const int c = cnt[i];
    row_ptr[i] = run;
    cursor[i] = run;
    run += c;
  }
  if (t == 1023) row_ptr[bins] = part[1023];
}

__global__ __launch_bounds__(256) void rgcn_scatter_kernel(
    const int* __restrict__ esrc, const int* __restrict__ edst,
    const int* __restrict__ etype, int* __restrict__ cursor,
    int* __restrict__ srec, int E) {
  for (int e = blockIdx.x * 256 + threadIdx.x; e < E; e += gridDim.x * 256) {
    const int d = edst[e];
    const int p = atomicAdd(&cursor[d], 1);
    srec[p] = (esrc[e] << 4) | etype[e];
  }
}

// One WAVE per destination node. Edges pre-sorted by dst (CSR row_ptr).
// lane = (b,o): b = lane>>4 (block for lo half; hi half uses b+4), o = lane&15.
// Accumulate the dst's 128-wide output in 2 VGPRs; non-atomic RMW + relu.
__global__ __launch_bounds__(256) void rgcn_gather_kernel(
    const float* __restrict__ h, const float* __restrict__ norm,
    const int* __restrict__ srec, const int* __restrict__ row_ptr,
    const float* __restrict__ wT, float* __restrict__ out, int N) {
  const int lane = threadIdx.x & 63;
  const int d = blockIdx.x * 4 + (threadIdx.x >> 6);
  if (d >= N) return;
  const int b = lane >> 4;
  const int o = lane & 15;

  const int e0 = row_ptr[d];
  const int e1 = row_ptr[d + 1];

  float acc0 = 0.f, acc1 = 0.f;

#pragma unroll 2
  for (int e = e0; e < e1; ++e) {
    const int rec = srec[e];
    const int src = rec >> 4;
    const int t = rec & 15;

    const float4* __restrict__ hp =
        (const float4*)(h + (size_t)src * 128) + (b << 2);
    const float4* __restrict__ wp =
        (const float4*)(wT + t * 2048 + b * 256 + (o << 4));

    const float4 x0 = hp[0], x1 = hp[1], x2 = hp[2], x3 = hp[3];
    const float4 y0 = hp[16], y1 = hp[17], y2 = hp[18], y3 = hp[19];
    const float4 w0 = wp[0], w1 = wp[1], w2 = wp[2], w3 = wp[3];
    const float4 v0 = wp[256], v1 = wp[257], v2 = wp[258], v3 = wp[259];

    acc0 = fmaf(x0.x, w0.x, acc0); acc0 = fmaf(x0.y, w0.y, acc0);
    acc0 = fmaf(x0.z, w0.z, acc0); acc0 = fmaf(x0.w, w0.w, acc0);
    acc0 = fmaf(x1.x, w1.x, acc0); acc0 = fmaf(x1.y, w1.y, acc0);
    acc0 = fmaf(x1.z, w1.z, acc0); acc0 = fmaf(x1.w, w1.w, acc0);
    acc0 = fmaf(x2.x, w2.x, acc0); acc0 = fmaf(x2.y, w2.y, acc0);
    acc0 = fmaf(x2.z, w2.z, acc0); acc0 = fmaf(x2.w, w2.w, acc0);
    acc0 = fmaf(x3.x, w3.x, acc0); acc0 = fmaf(x3.y, w3.y, acc0);
    acc0 = fmaf(x3.z, w3.z, acc0); acc0 = fmaf(x3.w, w3.w, acc0);

    acc1 = fmaf(y0.x, v0.x, acc1); acc1 = fmaf(y0.y, v0.y, acc1);
    acc1 = fmaf(y0.z, v0.z, acc1); acc1 = fmaf(y0.w, v0.w, acc1);
    acc1 = fmaf(y1.x, v1.x, acc1); acc1 = fmaf(y1.y, v1.y, acc1);
    acc1 = fmaf(y1.z, v1.z, acc1); acc1 = fmaf(y1.w, v1.w, acc1);
    acc1 = fmaf(y2.x, v2.x, acc1); acc1 = fmaf(y2.y, v2.y, acc1);
    acc1 = fmaf(y2.z, v2.z, acc1); acc1 = fmaf(y2.w, v2.w, acc1);
    acc1 = fmaf(y3.x, v3.x, acc1); acc1 = fmaf(y3.y, v3.y, acc1);
    acc1 = fmaf(y3.z, v3.z, acc1); acc1 = fmaf(y3.w, v3.w, acc1);
  }

  const float nm = norm[d];
  const size_t base = (size_t)d * 128;
  out[base + lane] = fmaxf(fmaf(acc0, nm, out[base + lane]), 0.f);
  out[base + 64 + lane] = fmaxf(fmaf(acc1, nm, out[base + 64 + lane]), 0.f);
}

// Fallback (ws too small / unexpected shape): unsorted atomic edge kernel.
__global__ __launch_bounds__(256) void rgcn_edge_kernel(
    const float* __restrict__ h, const float* __restrict__ norm,
    const int* __restrict__ esrc, const int* __restrict__ edst,
    const int* __restrict__ etype, const float* __restrict__ weight,
    float* __restrict__ out, int E) {
  const int lane = threadIdx.x & 63;
  const int wid = threadIdx.x >> 6;
  const int wave0 = blockIdx.x * 4 + wid;
  const int nwaves = gridDim.x * 4;
  const int b = lane >> 4;
  const int o = lane & 15;

  for (int e = wave0; e < E; e += nwaves) {
    const int src = esrc[e];
    const int dst = edst[e];
    const int et = etype[e];
    const float s_lo = h[src * 128 + lane];
    const float s_hi = h[src * 128 + 64 + lane];
    const float nrm = norm[dst];
    const float* __restrict__ Wb = weight + et * 2048 + b * 256 + o;
    float m0 = 0.f, m1 = 0.f;
#pragma unroll
    for (int i = 0; i < 16; ++i) {
      const float a_lo = __shfl(s_lo, (lane & 48) + i, 64);
      const float a_hi = __shfl(s_hi, (lane & 48) + i, 64);
      m0 = fmaf(a_lo, Wb[i * 16], m0);
      m1 = fmaf(a_hi, Wb[1024 + i * 16], m1);
    }
    atomicAdd(&out[dst * 128 + lane], m0 * nrm);
    atomicAdd(&out[dst * 128 + 64 + lane], m1 * nrm);
  }
}

__global__ __launch_bounds__(256) void rgcn_relu_kernel(float* __restrict__ out,
                                                        int total4) {
  int i = blockIdx.x * 256 + threadIdx.x;
  const int stride = gridDim.x * 256;
  for (; i < total4; i += stride) {
    float4 v = ((float4*)out)[i];
    v.x = fmaxf(v.x, 0.f);
    v.y = fmaxf(v.y, 0.f);
    v.z = fmaxf(v.z, 0.f);
    v.w = fmaxf(v.w, 0.f);
    ((float4*)out)[i] = v;
  }
}

extern "C" void kernel_launch(void* const* d_in, const int* in_sizes, int n_in,
                              void* d_out, int out_size, void* d_ws, size_t ws_size,
                              hipStream_t stream) {
  const float* h      = (const float*)d_in[0];
  const float* norm   = (const float*)d_in[1];
  const int*   esrc   = (const int*)d_in[2];
  const int*   edst   = (const int*)d_in[3];
  const int*   etype  = (const int*)d_in[4];
  const float* weight = (const float*)d_in[5];
  const float* bias   = (const float*)d_in[6];
  const float* loop_w = (const float*)d_in[7];
  float* out = (float*)d_out;

  const int N = in_sizes[0] / 128;
  const int E = in_sizes[2];
  const int nrels = in_sizes[5] / 2048;
  const int wtotal = in_sizes[5];

  rgcn_init_kernel<<<2048, 256, 0, stream>>>(h, loop_w, bias, out, N);

  // ws: cnt[N] | row_ptr[N+1] | (pad to 16B) cursor[N] | wT[32768] | srec[E]
  size_t ofs_cnt = 0;
  size_t ofs_rp = N;
  size_t ofs_cur = (ofs_rp + N + 1 + 3) & ~(size_t)3;
  size_t ofs_wT = (ofs_cur + N + 3) & ~(size_t)3;
  size_t ofs_srec = ofs_wT + (size_t)wtotal;
  const size_t need = (ofs_srec + (size_t)E) * 4;

  if (nrels == 16 && N < (1 << 26) && ws_size >= need) {
    int* base    = (int*)d_ws;
    int* cnt     = base + ofs_cnt;
    int* row_ptr = base + ofs_rp;
    int* cursor  = base + ofs_cur;
    float* wT    = (float*)(base + ofs_wT);
    int* srec    = base + ofs_srec;

    rgcn_transpose_w_kernel<<<32, 256, 0, stream>>>(weight, wT, wtotal);
    rgcn_zero_kernel<<<128, 256, 0, stream>>>(cnt, N);
    rgcn_hist_kernel<<<2048, 256, 0, stream>>>(edst, cnt, E);
    rgcn_scan_kernel<<<1, 1024, 0, stream>>>(cnt, row_ptr, cursor, N);
    rgcn_scatter_kernel<<<2048, 256, 0, stream>>>(esrc, edst, etype, cursor,
                                                  srec, E);
    rgcn_gather_kernel<<<(N + 3) / 4, 256, 0, stream>>>(h, norm, srec, row_ptr,
                                                        wT, out, N);
  } else {
    rgcn_edge_kernel<<<4096, 256, 0, stream>>>(h, norm, esrc, edst, etype,
                                               weight, out, E);
    rgcn_relu_kernel<<<2048, 256, 0, stream>>>(out, (N * 128) / 4);
  }
}

// Round 5
// 1418.993 us; speedup vs baseline: 1.1259x; 1.1259x over previous
//
#include <hip/hip_runtime.h>

// RGCN block-diagonal layer, f32.
// out = relu( (scatter_sum(msg) * norm) + bias + h @ loop_weight )
// msg[e, b*16+o] = sum_i h[src[e], b*16+i] * W[type[e], b*256 + i*16 + o]
//
// v5: dst-sorted CSR + PERSISTENT waves + software-pipelined, LDS-staged
// h-row batches (8 rows / 4 coalesced dwordx4 loads -> wave-private LDS).
//   A: init_kernel : out = bias + h @ loop_weight
//   T: transpose weights -> wT[t][bb][o][i]
//   Z/H/S/C: counting sort by dst -> row_ptr, srec[e]=(src<<4)|type
//   G: gather2 : wave owns dst range [w*N/W,(w+1)*N/W); streams its edge
//      range in batches of 8; flush = non-atomic RMW + fused relu.

#define RB 8  // edges per batch

__global__ __launch_bounds__(256) void rgcn_init_kernel(
    const float* __restrict__ h, const float* __restrict__ loop_w,
    const float* __restrict__ bias, float* __restrict__ out, int N) {
  __shared__ float lw[128 * 128];  // 64 KB
  for (int idx = threadIdx.x; idx < 128 * 128 / 4; idx += 256) {
    ((float4*)lw)[idx] = ((const float4*)loop_w)[idx];
  }
  __syncthreads();

  const int lane = threadIdx.x & 63;
  const int wid = threadIdx.x >> 6;
  const int group0 = blockIdx.x * 4 + wid;
  const int ngroups = gridDim.x * 4;
  const int totgroups = (N + 3) >> 2;
  const float b0 = bias[lane];
  const float b1 = bias[64 + lane];

  for (int g = group0; g < totgroups; g += ngroups) {
    const int n0 = g * 4;
    const int nn = (N - n0 < 4) ? (N - n0) : 4;
    if (nn == 4) {
      const float* __restrict__ r0 = h + (size_t)n0 * 128;
      const float* __restrict__ r1 = r0 + 128;
      const float* __restrict__ r2 = r1 + 128;
      const float* __restrict__ r3 = r2 + 128;
      float a00 = b0, a01 = b1, a10 = b0, a11 = b1;
      float a20 = b0, a21 = b1, a30 = b0, a31 = b1;
#pragma unroll 4
      for (int k = 0; k < 128; ++k) {
        const float w0 = lw[k * 128 + lane];
        const float w1 = lw[k * 128 + 64 + lane];
        a00 = fmaf(r0[k], w0, a00); a01 = fmaf(r0[k], w1, a01);
        a10 = fmaf(r1[k], w0, a10); a11 = fmaf(r1[k], w1, a11);
        a20 = fmaf(r2[k], w0, a20); a21 = fmaf(r2[k], w1, a21);
        a30 = fmaf(r3[k], w0, a30); a31 = fmaf(r3[k], w1, a31);
      }
      float* __restrict__ o0 = out + (size_t)n0 * 128;
      o0[lane] = a00;        o0[64 + lane] = a01;
      o0[128 + lane] = a10;  o0[192 + lane] = a11;
      o0[256 + lane] = a20;  o0[320 + lane] = a21;
      o0[384 + lane] = a30;  o0[448 + lane] = a31;
    } else {
      for (int r = 0; r < nn; ++r) {
        const int n = n0 + r;
        const float* __restrict__ hr = h + (size_t)n * 128;
        float a0 = b0, a1 = b1;
#pragma unroll 4
        for (int k = 0; k < 128; ++k) {
          const float a = hr[k];
          a0 = fmaf(a, lw[k * 128 + lane], a0);
          a1 = fmaf(a, lw[k * 128 + 64 + lane], a1);
        }
        out[(size_t)n * 128 + lane] = a0;
        out[(size_t)n * 128 + 64 + lane] = a1;
      }
    }
  }
}

// wT[t][bb][o][i] = weight[t][bb][i][o]
__global__ __launch_bounds__(256) void rgcn_transpose_w_kernel(
    const float* __restrict__ weight, float* __restrict__ wT, int total) {
  for (int idx = blockIdx.x * 256 + threadIdx.x; idx < total;
       idx += gridDim.x * 256) {
    const int t = idx >> 11;
    const int r = idx & 2047;
    const int bb = r >> 8;
    const int i = (r >> 4) & 15;
    const int o = r & 15;
    wT[t * 2048 + bb * 256 + o * 16 + i] = weight[idx];
  }
}

__global__ __launch_bounds__(256) void rgcn_zero_kernel(int* __restrict__ p,
                                                        int n) {
  for (int i = blockIdx.x * 256 + threadIdx.x; i < n; i += gridDim.x * 256)
    p[i] = 0;
}

__global__ __launch_bounds__(256) void rgcn_hist_kernel(
    const int* __restrict__ edst, int* __restrict__ cnt, int E) {
  for (int e = blockIdx.x * 256 + threadIdx.x; e < E; e += gridDim.x * 256)
    atomicAdd(&cnt[edst[e]], 1);
}

__global__ __launch_bounds__(1024) void rgcn_scan_kernel(
    const int* __restrict__ cnt, int* __restrict__ row_ptr,
    int* __restrict__ cursor, int bins) {
  __shared__ int part[1024];
  const int t = threadIdx.x;
  const int chunk = (bins + 1023) >> 10;
  const int lo = t * chunk;
  const int hi = min(bins, lo + chunk);
  int s = 0;
  for (int i = lo; i < hi; ++i) s += cnt[i];
  part[t] = s;
  __syncthreads();
#pragma unroll
  for (int off = 1; off < 1024; off <<= 1) {
    const int add = (t >= off) ? part[t - off] : 0;
    __syncthreads();
    part[t] += add;
    __syncthreads();
  }
  int run = (t == 0) ? 0 : part[t - 1];
  for (int i = lo; i < hi; ++i) {
    const int c = cnt[i];
    row_ptr[i] = run;
    cursor[i] = run;
    run += c;
  }
  if (t == 1023) row_ptr[bins] = part[1023];
}

__global__ __launch_bounds__(256) void rgcn_scatter_kernel(
    const int* __restrict__ esrc, const int* __restrict__ edst,
    const int* __restrict__ etype, int* __restrict__ cursor,
    int* __restrict__ srec, int E) {
  for (int e = blockIdx.x * 256 + threadIdx.x; e < E; e += gridDim.x * 256) {
    const int d = edst[e];
    const int p = atomicAdd(&cursor[d], 1);
    srec[p] = (esrc[e] << 4) | etype[e];
  }
}

// Persistent-wave gather with LDS-staged h-row batches.
// Wave = one contiguous dst range; edges pre-sorted by dst.
// Batch of 8 edges: 4 coalesced dwordx4 loads fetch 8 full 512-B h rows
// (2 rows/instr: lanes 0-31 row A, lanes 32-63 row B, 16 B/lane contiguous).
// Pipeline: stage batch k to LDS, issue batch k+1 global loads, compute k.
__global__ __launch_bounds__(256) void rgcn_gather2_kernel(
    const float* __restrict__ h, const float* __restrict__ norm,
    const int* __restrict__ srec, const int* __restrict__ row_ptr,
    const float* __restrict__ wT, float* __restrict__ out,
    int N, int E, int W) {
  __shared__ float hstage[4 * RB * 128];  // 16 KB: 4 waves x 8 rows x 512 B
  const int lane = threadIdx.x & 63;
  const int wl = threadIdx.x >> 6;
  const int wave = blockIdx.x * 4 + wl;
  if (wave >= W) return;
  float* __restrict__ buf = hstage + wl * (RB * 128);

  int d0 = (int)(((long)wave * N) / W);
  const int d1 = (int)(((long)(wave + 1) * N) / W);
  if (d0 >= d1) return;

  const int e0 = row_ptr[d0];
  const int e1 = row_ptr[d1];

  const int b = lane >> 4;    // block 0..3 (lo half; hi half = b+4)
  const int o = lane & 15;    // out col within block
  const int sub = lane >> 5;  // which row of the pair this lane loads
  const int f4 = lane & 31;   // 16-B chunk within the 512-B row
  const int Em1 = E - 1;

  int d = d0;
  int row_end = row_ptr[d + 1];
  float acc0 = 0.f, acc1 = 0.f;

  int rec[RB];
  float4 pf[4];

  auto loadregs = [&](int base) {
#pragma unroll
    for (int i = 0; i < RB; ++i) rec[i] = srec[min(base + i, Em1)];
#pragma unroll
    for (int j = 0; j < 4; ++j) {
      const int r = sub ? rec[2 * j + 1] : rec[2 * j];
      pf[j] = *((const float4*)(h + ((size_t)(r >> 4) << 7)) + f4);
    }
  };

  if (e0 < e1) loadregs(e0);

  for (int e = e0; e < e1; e += RB) {
    // stage current batch to wave-private LDS (no barrier needed)
#pragma unroll
    for (int j = 0; j < 4; ++j)
      ((float4*)buf)[(2 * j + sub) * 32 + f4] = pf[j];
    int rc[RB];
#pragma unroll
    for (int i = 0; i < RB; ++i) rc[i] = rec[i];
    // issue next batch's global loads; latency hides under compute below
    if (e + RB < e1) loadregs(e + RB);

#pragma unroll
    for (int i = 0; i < RB; ++i) {
      const int g = e + i;
      if (g < e1) {
        while (g >= row_end) {  // crossed row boundary: flush d (uniform)
          const float nm = norm[d];
          float* __restrict__ op = out + ((size_t)d << 7);
          op[lane] = fmaxf(fmaf(acc0, nm, op[lane]), 0.f);
          op[64 + lane] = fmaxf(fmaf(acc1, nm, op[64 + lane]), 0.f);
          acc0 = 0.f; acc1 = 0.f;
          ++d;
          row_end = row_ptr[d + 1];
        }
        const int t = rc[i] & 15;
        const float4* __restrict__ wp =
            (const float4*)(wT + t * 2048 + b * 256 + (o << 4));
        const float4 w0 = wp[0], w1 = wp[1], w2 = wp[2], w3 = wp[3];
        const float4 v0 = wp[256], v1 = wp[257], v2 = wp[258], v3 = wp[259];
        const float4* __restrict__ hl = (const float4*)buf + i * 32 + (b << 2);
        const float4 x0 = hl[0], x1 = hl[1], x2 = hl[2], x3 = hl[3];
        const float4 y0 = hl[16], y1 = hl[17], y2 = hl[18], y3 = hl[19];

        acc0 = fmaf(x0.x, w0.x, acc0); acc0 = fmaf(x0.y, w0.y, acc0);
        acc0 = fmaf(x0.z, w0.z, acc0); acc0 = fmaf(x0.w, w0.w, acc0);
        acc0 = fmaf(x1.x, w1.x, acc0); acc0 = fmaf(x1.y, w1.y, acc0);
        acc0 = fmaf(x1.z, w1.z, acc0); acc0 = fmaf(x1.w, w1.w, acc0);
        acc0 = fmaf(x2.x, w2.x, acc0); acc0 = fmaf(x2.y, w2.y, acc0);
        acc0 = fmaf(x2.z, w2.z, acc0); acc0 = fmaf(x2.w, w2.w, acc0);
        acc0 = fmaf(x3.x, w3.x, acc0); acc0 = fmaf(x3.y, w3.y, acc0);
        acc0 = fmaf(x3.z, w3.z, acc0); acc0 = fmaf(x3.w, w3.w, acc0);

        acc1 = fmaf(y0.x, v0.x, acc1); acc1 = fmaf(y0.y, v0.y, acc1);
        acc1 = fmaf(y0.z, v0.z, acc1); acc1 = fmaf(y0.w, v0.w, acc1);
        acc1 = fmaf(y1.x, v1.x, acc1); acc1 = fmaf(y1.y, v1.y, acc1);
        acc1 = fmaf(y1.z, v1.z, acc1); acc1 = fmaf(y1.w, v1.w, acc1);
        acc1 = fmaf(y2.x, v2.x, acc1); acc1 = fmaf(y2.y, v2.y, acc1);
        acc1 = fmaf(y2.z, v2.z, acc1); acc1 = fmaf(y2.w, v2.w, acc1);
        acc1 = fmaf(y3.x, v3.x, acc1); acc1 = fmaf(y3.y, v3.y, acc1);
        acc1 = fmaf(y3.z, v3.z, acc1); acc1 = fmaf(y3.w, v3.w, acc1);
      }
    }
  }

  // flush remaining dsts in range (incl. zero-degree rows: relu still applies)
  while (d < d1) {
    const float nm = norm[d];
    float* __restrict__ op = out + ((size_t)d << 7);
    op[lane] = fmaxf(fmaf(acc0, nm, op[lane]), 0.f);
    op[64 + lane] = fmaxf(fmaf(acc1, nm, op[64 + lane]), 0.f);
    acc0 = 0.f; acc1 = 0.f;
    ++d;
  }
}

// Fallback (ws too small / unexpected shape): unsorted atomic edge kernel.
__global__ __launch_bounds__(256) void rgcn_edge_kernel(
    const float* __restrict__ h, const float* __restrict__ norm,
    const int* __restrict__ esrc, const int* __restrict__ edst,
    const int* __restrict__ etype, const float* __restrict__ weight,
    float* __restrict__ out, int E) {
  const int lane = threadIdx.x & 63;
  const int wid = threadIdx.x >> 6;
  const int wave0 = blockIdx.x * 4 + wid;
  const int nwaves = gridDim.x * 4;
  const int b = lane >> 4;
  const int o = lane & 15;

  for (int e = wave0; e < E; e += nwaves) {
    const int src = esrc[e];
    const int dst = edst[e];
    const int et = etype[e];
    const float s_lo = h[src * 128 + lane];
    const float s_hi = h[src * 128 + 64 + lane];
    const float nrm = norm[dst];
    const float* __restrict__ Wb = weight + et * 2048 + b * 256 + o;
    float m0 = 0.f, m1 = 0.f;
#pragma unroll
    for (int i = 0; i < 16; ++i) {
      const float a_lo = __shfl(s_lo, (lane & 48) + i, 64);
      const float a_hi = __shfl(s_hi, (lane & 48) + i, 64);
      m0 = fmaf(a_lo, Wb[i * 16], m0);
      m1 = fmaf(a_hi, Wb[1024 + i * 16], m1);
    }
    atomicAdd(&out[dst * 128 + lane], m0 * nrm);
    atomicAdd(&out[dst * 128 + 64 + lane], m1 * nrm);
  }
}

__global__ __launch_bounds__(256) void rgcn_relu_kernel(float* __restrict__ out,
                                                        int total4) {
  int i = blockIdx.x * 256 + threadIdx.x;
  const int stride = gridDim.x * 256;
  for (; i < total4; i += stride) {
    float4 v = ((float4*)out)[i];
    v.x = fmaxf(v.x, 0.f);
    v.y = fmaxf(v.y, 0.f);
    v.z = fmaxf(v.z, 0.f);
    v.w = fmaxf(v.w, 0.f);
    ((float4*)out)[i] = v;
  }
}

extern "C" void kernel_launch(void* const* d_in, const int* in_sizes, int n_in,
                              void* d_out, int out_size, void* d_ws, size_t ws_size,
                              hipStream_t stream) {
  const float* h      = (const float*)d_in[0];
  const float* norm   = (const float*)d_in[1];
  const int*   esrc   = (const int*)d_in[2];
  const int*   edst   = (const int*)d_in[3];
  const int*   etype  = (const int*)d_in[4];
  const float* weight = (const float*)d_in[5];
  const float* bias   = (const float*)d_in[6];
  const float* loop_w = (const float*)d_in[7];
  float* out = (float*)d_out;

  const int N = in_sizes[0] / 128;
  const int E = in_sizes[2];
  const int nrels = in_sizes[5] / 2048;
  const int wtotal = in_sizes[5];

  rgcn_init_kernel<<<2048, 256, 0, stream>>>(h, loop_w, bias, out, N);

  // ws: cnt[N] | row_ptr[N+1] | (pad) cursor[N] | wT[32768] | srec[E]
  size_t ofs_cnt = 0;
  size_t ofs_rp = N;
  size_t ofs_cur = (ofs_rp + N + 1 + 3) & ~(size_t)3;
  size_t ofs_wT = (ofs_cur + N + 3) & ~(size_t)3;
  size_t ofs_srec = ofs_wT + (size_t)wtotal;
  const size_t need = (ofs_srec + (size_t)E) * 4;

  if (nrels == 16 && N < (1 << 26) && ws_size >= need) {
    int* base    = (int*)d_ws;
    int* cnt     = base + ofs_cnt;
    int* row_ptr = base + ofs_rp;
    int* cursor  = base + ofs_cur;
    float* wT    = (float*)(base + ofs_wT);
    int* srec    = base + ofs_srec;

    rgcn_transpose_w_kernel<<<32, 256, 0, stream>>>(weight, wT, wtotal);
    rgcn_zero_kernel<<<128, 256, 0, stream>>>(cnt, N);
    rgcn_hist_kernel<<<2048, 256, 0, stream>>>(edst, cnt, E);
    rgcn_scan_kernel<<<1, 1024, 0, stream>>>(cnt, row_ptr, cursor, N);
    rgcn_scatter_kernel<<<2048, 256, 0, stream>>>(esrc, edst, etype, cursor,
                                                  srec, E);
    const int W = 8192;  // persistent waves
    rgcn_gather2_kernel<<<W / 4, 256, 0, stream>>>(h, norm, srec, row_ptr, wT,
                                                   out, N, E, W);
  } else {
    rgcn_edge_kernel<<<4096, 256, 0, stream>>>(h, norm, esrc, edst, etype,
                                               weight, out, E);
    rgcn_relu_kernel<<<2048, 256, 0, stream>>>(out, (N * 128) / 4);
  }
}

// Round 6
// 928.796 us; speedup vs baseline: 1.7202x; 1.5278x over previous
//
#include <hip/hip_runtime.h>

// RGCN block-diagonal layer, f32.
// out = relu( (scatter_sum(msg) * norm) + bias + h @ loop_weight )
// msg[e, b*16+o] = sum_i h[src[e], b*16+i] * W[type[e], b*256 + i*16 + o]
//
// v6: precompute ALL per-(node,type) messages densely, then gather-add.
//   A: init_kernel  : out = bias + h @ loop_weight          (LDS-staged LW)
//   P: precompute   : M[n*16+t][lane] = bf16pack( (h[n]·W[t])[lane],
//                                                 (h[n]·W[t])[64+lane] )
//                     wave=type (weights in 32 VGPRs), h read sequentially
//   Z/H/S/C: counting sort by dst -> row_ptr CSR, srec[e]=(src<<4)|type
//   G: gather3      : wave per dst: acc += unpack(M[srec[e]]) ; flush =
//                     out[d] = relu(out[d] + acc*norm[d])    (non-atomic)

__device__ __forceinline__ unsigned int f2bf(float f) {
  const unsigned int u = __float_as_uint(f);
  return (u + 0x7FFFu + ((u >> 16) & 1u)) >> 16;  // round-nearest-even
}

__global__ __launch_bounds__(256) void rgcn_init_kernel(
    const float* __restrict__ h, const float* __restrict__ loop_w,
    const float* __restrict__ bias, float* __restrict__ out, int N) {
  __shared__ float lw[128 * 128];  // 64 KB
  for (int idx = threadIdx.x; idx < 128 * 128 / 4; idx += 256) {
    ((float4*)lw)[idx] = ((const float4*)loop_w)[idx];
  }
  __syncthreads();

  const int lane = threadIdx.x & 63;
  const int wid = threadIdx.x >> 6;
  const int group0 = blockIdx.x * 4 + wid;
  const int ngroups = gridDim.x * 4;
  const int totgroups = (N + 3) >> 2;
  const float b0 = bias[lane];
  const float b1 = bias[64 + lane];

  for (int g = group0; g < totgroups; g += ngroups) {
    const int n0 = g * 4;
    const int nn = (N - n0 < 4) ? (N - n0) : 4;
    if (nn == 4) {
      const float* __restrict__ r0 = h + (size_t)n0 * 128;
      const float* __restrict__ r1 = r0 + 128;
      const float* __restrict__ r2 = r1 + 128;
      const float* __restrict__ r3 = r2 + 128;
      float a00 = b0, a01 = b1, a10 = b0, a11 = b1;
      float a20 = b0, a21 = b1, a30 = b0, a31 = b1;
#pragma unroll 4
      for (int k = 0; k < 128; ++k) {
        const float w0 = lw[k * 128 + lane];
        const float w1 = lw[k * 128 + 64 + lane];
        a00 = fmaf(r0[k], w0, a00); a01 = fmaf(r0[k], w1, a01);
        a10 = fmaf(r1[k], w0, a10); a11 = fmaf(r1[k], w1, a11);
        a20 = fmaf(r2[k], w0, a20); a21 = fmaf(r2[k], w1, a21);
        a30 = fmaf(r3[k], w0, a30); a31 = fmaf(r3[k], w1, a31);
      }
      float* __restrict__ o0 = out + (size_t)n0 * 128;
      o0[lane] = a00;        o0[64 + lane] = a01;
      o0[128 + lane] = a10;  o0[192 + lane] = a11;
      o0[256 + lane] = a20;  o0[320 + lane] = a21;
      o0[384 + lane] = a30;  o0[448 + lane] = a31;
    } else {
      for (int r = 0; r < nn; ++r) {
        const int n = n0 + r;
        const float* __restrict__ hr = h + (size_t)n * 128;
        float a0 = b0, a1 = b1;
#pragma unroll 4
        for (int k = 0; k < 128; ++k) {
          const float a = hr[k];
          a0 = fmaf(a, lw[k * 128 + lane], a0);
          a1 = fmaf(a, lw[k * 128 + 64 + lane], a1);
        }
        out[(size_t)n * 128 + lane] = a0;
        out[(size_t)n * 128 + 64 + lane] = a1;
      }
    }
  }
}

// Phase P: 1024-thread blocks; wave = one relation type (weights stay in
// 32 VGPRs for the whole kernel). h rows read sequentially (L1-shared by
// the 16 waves); one coalesced dword store per node per wave.
__global__ __launch_bounds__(1024) void rgcn_precompute_kernel(
    const float* __restrict__ h, const float* __restrict__ weight,
    unsigned int* __restrict__ M, int N) {
  const int lane = threadIdx.x & 63;
  const int t = threadIdx.x >> 6;  // wave index = type 0..15
  const int b = lane >> 4;         // block 0..3 (lo half); hi half = b+4
  const int o = lane & 15;

  const float* __restrict__ wb = weight + t * 2048 + b * 256 + o;
  float wlo[16], whi[16];
#pragma unroll
  for (int i = 0; i < 16; ++i) {
    wlo[i] = wb[i * 16];
    whi[i] = wb[1024 + i * 16];
  }

  const int n0 = (int)(((long)blockIdx.x * N) / gridDim.x);
  const int n1 = (int)(((long)(blockIdx.x + 1) * N) / gridDim.x);

#pragma unroll 2
  for (int n = n0; n < n1; ++n) {
    const float4* __restrict__ hp =
        (const float4*)(h + (size_t)n * 128) + (b << 2);
    const float4 x0 = hp[0], x1 = hp[1], x2 = hp[2], x3 = hp[3];
    const float4 y0 = hp[16], y1 = hp[17], y2 = hp[18], y3 = hp[19];

    float a0 = x0.x * wlo[0], a1 = x0.y * wlo[1];
    a0 = fmaf(x0.z, wlo[2], a0);  a1 = fmaf(x0.w, wlo[3], a1);
    a0 = fmaf(x1.x, wlo[4], a0);  a1 = fmaf(x1.y, wlo[5], a1);
    a0 = fmaf(x1.z, wlo[6], a0);  a1 = fmaf(x1.w, wlo[7], a1);
    a0 = fmaf(x2.x, wlo[8], a0);  a1 = fmaf(x2.y, wlo[9], a1);
    a0 = fmaf(x2.z, wlo[10], a0); a1 = fmaf(x2.w, wlo[11], a1);
    a0 = fmaf(x3.x, wlo[12], a0); a1 = fmaf(x3.y, wlo[13], a1);
    a0 = fmaf(x3.z, wlo[14], a0); a1 = fmaf(x3.w, wlo[15], a1);

    float c0 = y0.x * whi[0], c1 = y0.y * whi[1];
    c0 = fmaf(y0.z, whi[2], c0);  c1 = fmaf(y0.w, whi[3], c1);
    c0 = fmaf(y1.x, whi[4], c0);  c1 = fmaf(y1.y, whi[5], c1);
    c0 = fmaf(y1.z, whi[6], c0);  c1 = fmaf(y1.w, whi[7], c1);
    c0 = fmaf(y2.x, whi[8], c0);  c1 = fmaf(y2.y, whi[9], c1);
    c0 = fmaf(y2.z, whi[10], c0); c1 = fmaf(y2.w, whi[11], c1);
    c0 = fmaf(y3.x, whi[12], c0); c1 = fmaf(y3.y, whi[13], c1);
    c0 = fmaf(y3.z, whi[14], c0); c1 = fmaf(y3.w, whi[15], c1);

    const unsigned int pk = f2bf(a0 + a1) | (f2bf(c0 + c1) << 16);
    M[(((size_t)n << 4) | t) * 64 + lane] = pk;
  }
}

__global__ __launch_bounds__(256) void rgcn_zero_kernel(int* __restrict__ p,
                                                        int n) {
  for (int i = blockIdx.x * 256 + threadIdx.x; i < n; i += gridDim.x * 256)
    p[i] = 0;
}

__global__ __launch_bounds__(256) void rgcn_hist_kernel(
    const int* __restrict__ edst, int* __restrict__ cnt, int E) {
  for (int e = blockIdx.x * 256 + threadIdx.x; e < E; e += gridDim.x * 256)
    atomicAdd(&cnt[edst[e]], 1);
}

__global__ __launch_bounds__(1024) void rgcn_scan_kernel(
    const int* __restrict__ cnt, int* __restrict__ row_ptr,
    int* __restrict__ cursor, int bins) {
  __shared__ int part[1024];
  const int t = threadIdx.x;
  const int chunk = (bins + 1023) >> 10;
  const int lo = t * chunk;
  const int hi = min(bins, lo + chunk);
  int s = 0;
  for (int i = lo; i < hi; ++i) s += cnt[i];
  part[t] = s;
  __syncthreads();
#pragma unroll
  for (int off = 1; off < 1024; off <<= 1) {
    const int add = (t >= off) ? part[t - off] : 0;
    __syncthreads();
    part[t] += add;
    __syncthreads();
  }
  int run = (t == 0) ? 0 : part[t - 1];
  for (int i = lo; i < hi; ++i) {
    const int c = cnt[i];
    row_ptr[i] = run;
    cursor[i] = run;
    run += c;
  }
  if (t == 1023) row_ptr[bins] = part[1023];
}

__global__ __launch_bounds__(256) void rgcn_scatter_kernel(
    const int* __restrict__ esrc, const int* __restrict__ edst,
    const int* __restrict__ etype, int* __restrict__ cursor,
    int* __restrict__ srec, int E) {
  for (int e = blockIdx.x * 256 + threadIdx.x; e < E; e += gridDim.x * 256) {
    const int d = edst[e];
    const int p = atomicAdd(&cursor[d], 1);
    srec[p] = (esrc[e] << 4) | etype[e];
  }
}

// Phase G: one wave per dst. Per edge: ONE coalesced dword load of the
// precomputed bf16-packed message row + 2 adds. No weights, no FMA chain.
__global__ __launch_bounds__(256) void rgcn_gather3_kernel(
    const float* __restrict__ norm, const int* __restrict__ srec,
    const int* __restrict__ row_ptr, const unsigned int* __restrict__ M,
    float* __restrict__ out, int N) {
  const int lane = threadIdx.x & 63;
  const int d = blockIdx.x * 4 + (threadIdx.x >> 6);
  if (d >= N) return;

  const int e0 = row_ptr[d];
  const int e1 = row_ptr[d + 1];
  float acc0 = 0.f, acc1 = 0.f;

  int e = e0;
  for (; e + 4 <= e1; e += 4) {
    const int r0 = srec[e], r1 = srec[e + 1], r2 = srec[e + 2],
              r3 = srec[e + 3];
    const unsigned int v0 = M[(size_t)r0 * 64 + lane];
    const unsigned int v1 = M[(size_t)r1 * 64 + lane];
    const unsigned int v2 = M[(size_t)r2 * 64 + lane];
    const unsigned int v3 = M[(size_t)r3 * 64 + lane];
    acc0 += __uint_as_float(v0 << 16);
    acc1 += __uint_as_float(v0 & 0xFFFF0000u);
    acc0 += __uint_as_float(v1 << 16);
    acc1 += __uint_as_float(v1 & 0xFFFF0000u);
    acc0 += __uint_as_float(v2 << 16);
    acc1 += __uint_as_float(v2 & 0xFFFF0000u);
    acc0 += __uint_as_float(v3 << 16);
    acc1 += __uint_as_float(v3 & 0xFFFF0000u);
  }
  for (; e < e1; ++e) {
    const unsigned int v = M[(size_t)srec[e] * 64 + lane];
    acc0 += __uint_as_float(v << 16);
    acc1 += __uint_as_float(v & 0xFFFF0000u);
  }

  const float nm = norm[d];
  float* __restrict__ op = out + ((size_t)d << 7);
  op[lane] = fmaxf(fmaf(acc0, nm, op[lane]), 0.f);
  op[64 + lane] = fmaxf(fmaf(acc1, nm, op[64 + lane]), 0.f);
}

// Fallback (ws too small / unexpected shape): unsorted atomic edge kernel.
__global__ __launch_bounds__(256) void rgcn_edge_kernel(
    const float* __restrict__ h, const float* __restrict__ norm,
    const int* __restrict__ esrc, const int* __restrict__ edst,
    const int* __restrict__ etype, const float* __restrict__ weight,
    float* __restrict__ out, int E) {
  const int lane = threadIdx.x & 63;
  const int wid = threadIdx.x >> 6;
  const int wave0 = blockIdx.x * 4 + wid;
  const int nwaves = gridDim.x * 4;
  const int b = lane >> 4;
  const int o = lane & 15;

  for (int e = wave0; e < E; e += nwaves) {
    const int src = esrc[e];
    const int dst = edst[e];
    const int et = etype[e];
    const float s_lo = h[src * 128 + lane];
    const float s_hi = h[src * 128 + 64 + lane];
    const float nrm = norm[dst];
    const float* __restrict__ Wb = weight + et * 2048 + b * 256 + o;
    float m0 = 0.f, m1 = 0.f;
#pragma unroll
    for (int i = 0; i < 16; ++i) {
      const float a_lo = __shfl(s_lo, (lane & 48) + i, 64);
      const float a_hi = __shfl(s_hi, (lane & 48) + i, 64);
      m0 = fmaf(a_lo, Wb[i * 16], m0);
      m1 = fmaf(a_hi, Wb[1024 + i * 16], m1);
    }
    atomicAdd(&out[dst * 128 + lane], m0 * nrm);
    atomicAdd(&out[dst * 128 + 64 + lane], m1 * nrm);
  }
}

__global__ __launch_bounds__(256) void rgcn_relu_kernel(float* __restrict__ out,
                                                        int total4) {
  int i = blockIdx.x * 256 + threadIdx.x;
  const int stride = gridDim.x * 256;
  for (; i < total4; i += stride) {
    float4 v = ((float4*)out)[i];
    v.x = fmaxf(v.x, 0.f);
    v.y = fmaxf(v.y, 0.f);
    v.z = fmaxf(v.z, 0.f);
    v.w = fmaxf(v.w, 0.f);
    ((float4*)out)[i] = v;
  }
}

extern "C" void kernel_launch(void* const* d_in, const int* in_sizes, int n_in,
                              void* d_out, int out_size, void* d_ws, size_t ws_size,
                              hipStream_t stream) {
  const float* h      = (const float*)d_in[0];
  const float* norm   = (const float*)d_in[1];
  const int*   esrc   = (const int*)d_in[2];
  const int*   edst   = (const int*)d_in[3];
  const int*   etype  = (const int*)d_in[4];
  const float* weight = (const float*)d_in[5];
  const float* bias   = (const float*)d_in[6];
  const float* loop_w = (const float*)d_in[7];
  float* out = (float*)d_out;

  const int N = in_sizes[0] / 128;
  const int E = in_sizes[2];
  const int nrels = in_sizes[5] / 2048;

  rgcn_init_kernel<<<2048, 256, 0, stream>>>(h, loop_w, bias, out, N);

  // ws (dwords): cnt[N] | row_ptr[N+1] | cursor[N] | srec[E] | M[N*16*64]
  const size_t ofs_cnt = 0;
  const size_t ofs_rp = ofs_cnt + (size_t)N;
  const size_t ofs_cur = (ofs_rp + N + 1 + 3) & ~(size_t)3;
  const size_t ofs_srec = (ofs_cur + N + 3) & ~(size_t)3;
  const size_t ofs_M = (ofs_srec + E + 15) & ~(size_t)15;
  const size_t need = (ofs_M + ((size_t)N << 4) * 64) * 4;

  if (nrels == 16 && N < (1 << 26) && ws_size >= need) {
    int* base    = (int*)d_ws;
    int* cnt     = base + ofs_cnt;
    int* row_ptr = base + ofs_rp;
    int* cursor  = base + ofs_cur;
    int* srec    = base + ofs_srec;
    unsigned int* M = (unsigned int*)(base + ofs_M);

    rgcn_precompute_kernel<<<512, 1024, 0, stream>>>(h, weight, M, N);
    rgcn_zero_kernel<<<128, 256, 0, stream>>>(cnt, N);
    rgcn_hist_kernel<<<2048, 256, 0, stream>>>(edst, cnt, E);
    rgcn_scan_kernel<<<1, 1024, 0, stream>>>(cnt, row_ptr, cursor, N);
    rgcn_scatter_kernel<<<2048, 256, 0, stream>>>(esrc, edst, etype, cursor,
                                                  srec, E);
    rgcn_gather3_kernel<<<(N + 3) / 4, 256, 0, stream>>>(norm, srec, row_ptr,
                                                         M, out, N);
  } else {
    rgcn_edge_kernel<<<4096, 256, 0, stream>>>(h, norm, esrc, edst, etype,
                                               weight, out, E);
    rgcn_relu_kernel<<<2048, 256, 0, stream>>>(out, (N * 128) / 4);
  }
}